// Round 6
// baseline (192.219 us; speedup 1.0000x reference)
//
#include <hip/hip_runtime.h>
#include <hip/hip_bf16.h>
#include <stdint.h>

#define B_DIM 8192
#define I_DIM 1024
#define H_DIM 1024
#define KTOT  2048
#define NTILES 32          // KTOT / 64

typedef __attribute__((ext_vector_type(8))) short short8;
typedef __attribute__((ext_vector_type(4))) float f32x4;

static __device__ __forceinline__ short f2b(float f) {
    __bf16 h = (__bf16)f;
    return __builtin_bit_cast(short, h);
}

static __device__ __forceinline__ short8 pack8(float4 a, float4 b) {
    short8 s;
    s[0] = f2b(a.x); s[1] = f2b(a.y); s[2] = f2b(a.z); s[3] = f2b(a.w);
    s[4] = f2b(b.x); s[5] = f2b(b.y); s[6] = f2b(b.z); s[7] = f2b(b.w);
    return s;
}

static __device__ __forceinline__ float sigmoid_f(float x) {
    return 1.0f / (1.0f + __expf(-x));
}

static __device__ __forceinline__ float tanh_fast(float x) {
    x = fminf(fmaxf(x, -15.0f), 15.0f);
    float e = __expf(2.0f * x);
    return (e - 1.0f) / (e + 1.0f);
}

static __device__ __forceinline__ void load_lds16(const void* gptr, void* lptr) {
    __builtin_amdgcn_global_load_lds(
        (const __attribute__((address_space(1))) uint32_t*)gptr,
        (__attribute__((address_space(3))) uint32_t*)lptr, 16, 0, 0);
}

// ---------------------------------------------------------------------------
// Pass 1: fp32 -> bf16 conversion into workspace (row-major).
//   A_ws [8192][2048]: k<1024 from x, k>=1024 from hprev
//   B_ws [4096][2048]: row n = gate*1024+h; k<1024 from Wx, k>=1024 from Wh
// ---------------------------------------------------------------------------
__global__ __launch_bounds__(256) void convert_kernel(
    const float* __restrict__ x, const float* __restrict__ h,
    const float* __restrict__ wx, const float* __restrict__ wh,
    short* __restrict__ Aw, short* __restrict__ Bw)
{
    const int64_t nx = (int64_t)B_DIM * I_DIM / 8;
    const int64_t nw = (int64_t)4 * H_DIM * I_DIM / 8;
    const int64_t total = 2 * nx + 2 * nw;
    for (int64_t g = (int64_t)blockIdx.x * blockDim.x + threadIdx.x; g < total;
         g += (int64_t)gridDim.x * blockDim.x) {
        const float* src;
        short* dst;
        if (g < nx) {
            int64_t r = g >> 7, kc = (g & 127) * 8;
            src = x + g * 8; dst = Aw + r * 2048 + kc;
        } else if (g < 2 * nx) {
            int64_t gg = g - nx;
            int64_t r = gg >> 7, kc = (gg & 127) * 8;
            src = h + gg * 8; dst = Aw + r * 2048 + 1024 + kc;
        } else if (g < 2 * nx + nw) {
            int64_t gg = g - 2 * nx;
            int64_t r = gg >> 7, kc = (gg & 127) * 8;
            src = wx + gg * 8; dst = Bw + r * 2048 + kc;
        } else {
            int64_t gg = g - 2 * nx - nw;
            int64_t r = gg >> 7, kc = (gg & 127) * 8;
            src = wh + gg * 8; dst = Bw + r * 2048 + 1024 + kc;
        }
        float4 v0 = ((const float4*)src)[0];
        float4 v1 = ((const float4*)src)[1];
        *(short8*)dst = pack8(v0, v1);
    }
}

// ---------------------------------------------------------------------------
// Pass 2: 256x256-tile GEMM, BK=64. ONE barrier + ONE vmcnt(0) per K-tile;
// ds_reads software-pipelined one sub-phase ahead into rotating register
// buffers so the per-CU LDS drain hides under the MFMA bursts (compiler's
// counted lgkm waits give each MFMA only its own operands).
// Fragment-tile LDS (zero bank conflicts). Fused in-register LSTM epilogue.
// 512 threads = 8 waves (2 M x 4 N); per-wave output 128 x 64 (4 gates x 16 h).
// LDS 128 KiB: A[2 dbuf][2 khalf][16 fragtile][1 KiB], B likewise.
// ---------------------------------------------------------------------------

#define AOFF(d, kp, f) ((d) * 16384 + (kp) * 8192 + (f) * 512)
#define BOFF(d, kp, f) (32768 + (d) * 16384 + (kp) * 8192 + (f) * 512)

#define STAGE_A(dn, kh, tkp) \
    load_lds16(aSrc0 + (size_t)(tkp) * 64 + (kh) * 32, &smem[AOFF(dn, kh, 2 * w)]); \
    load_lds16(aSrc1 + (size_t)(tkp) * 64 + (kh) * 32, &smem[AOFF(dn, kh, 2 * w + 1)]);

#define STAGE_B(dn, kh, tkp) \
    load_lds16(bSrc0 + (size_t)(tkp) * 64 + (kh) * 32, &smem[BOFF(dn, kh, 2 * w)]); \
    load_lds16(bSrc1 + (size_t)(tkp) * 64 + (kh) * 32, &smem[BOFF(dn, kh, 2 * w + 1)]);

#define RD_B(d, kp, BV) { \
    _Pragma("unroll") \
    for (int j = 0; j < 4; ++j) \
        BV[j] = *(const short8*)&smem[BOFF(d, kp, wn * 4 + j) + lane * 8]; }

#define RD_A(d, kp, mh, AV) { \
    _Pragma("unroll") \
    for (int i = 0; i < 4; ++i) \
        AV[i] = *(const short8*)&smem[AOFF(d, kp, wm * 8 + (mh) * 4 + i) + lane * 8]; }

#define MFMA16(mh, AV, BV) { \
    __builtin_amdgcn_s_setprio(1); \
    _Pragma("unroll") \
    for (int i = 0; i < 4; ++i) \
        _Pragma("unroll") \
        for (int j = 0; j < 4; ++j) \
            acc[(mh) * 4 + i][j] = __builtin_amdgcn_mfma_f32_16x16x32_bf16( \
                AV[i], BV[j], acc[(mh) * 4 + i][j], 0, 0, 0); \
    __builtin_amdgcn_s_setprio(0); }

// One K-tile. Sub-phases: R1 -> stage(next) -> R2 -> M1 -> R3 -> M2 -> R4
// -> M3 -> M4 -> vmcnt(0) -> barrier. Rotating reg buffers av0/av1/av2.
#define TILE(d, tn) do { \
    RD_B(d, 0, bv0) \
    RD_A(d, 0, 0, av0) \
    STAGE_A(d ^ 1, 0, tn) \
    STAGE_B(d ^ 1, 0, tn) \
    STAGE_A(d ^ 1, 1, tn) \
    STAGE_B(d ^ 1, 1, tn) \
    RD_A(d, 0, 1, av1) \
    MFMA16(0, av0, bv0) \
    RD_B(d, 1, bv1) \
    RD_A(d, 1, 0, av2) \
    MFMA16(1, av1, bv0) \
    RD_A(d, 1, 1, av0) \
    MFMA16(0, av2, bv1) \
    MFMA16(1, av0, bv1) \
    asm volatile("s_waitcnt vmcnt(0)" ::: "memory"); \
    __builtin_amdgcn_s_barrier(); \
} while (0)

__global__ __launch_bounds__(512, 2) void lstm_gemm8_kernel(
    const short* __restrict__ Aw, const short* __restrict__ Bw,
    const float* __restrict__ cprev, const float* __restrict__ bh,
    float* __restrict__ out)
{
    extern __shared__ __align__(16) short smem[];

    // XCD-aware swizzle: 512 blocks, 8 XCDs, bijective
    int bid = blockIdx.x;
    bid = (bid & 7) * 64 + (bid >> 3);
    const int bm = bid >> 4;     // 0..31  M-tile (256 rows)
    const int bn = bid & 15;     // 0..15  h-tile (64 h)
    const int m0 = bm * 256;
    const int h0 = bn * 64;

    const int t    = threadIdx.x;
    const int lane = t & 63;
    const int w    = t >> 6;     // wave 0..7
    const int wm   = w >> 2;     // 0..1
    const int wn   = w & 3;      // 0..3
    const int lc   = lane & 15;
    const int lk   = lane >> 4;  // k-slot 0..3

    // staging sources: wave w stages fragment-tiles f = 2w, 2w+1 of each half.
    const short* aSrc0 = Aw + (size_t)(m0 + (2 * w + 0) * 16 + lc) * 2048 + lk * 8;
    const short* aSrc1 = Aw + (size_t)(m0 + (2 * w + 1) * 16 + lc) * 2048 + lk * 8;
    const int cf0 = 2 * w, cf1 = 2 * w + 1;
    const short* bSrc0 = Bw + (size_t)((cf0 & 3) * 1024 + h0 + ((cf0 >> 2) << 4) + lc) * 2048 + lk * 8;
    const short* bSrc1 = Bw + (size_t)((cf1 & 3) * 1024 + h0 + ((cf1 >> 2) << 4) + lc) * 2048 + lk * 8;

    f32x4 acc[8][4] = {};   // [m-frag][gate]
    short8 av0[4], av1[4], av2[4], bv0[4], bv1[4];

    // prologue: stage tile 0 fully into dbuf 0, drain
    STAGE_A(0, 0, 0)
    STAGE_B(0, 0, 0)
    STAGE_A(0, 1, 0)
    STAGE_B(0, 1, 0)
    asm volatile("s_waitcnt vmcnt(0)" ::: "memory");
    __builtin_amdgcn_s_barrier();

    #pragma unroll 1
    for (int tk2 = 0; tk2 < 16; ++tk2) {
        const int t1  = 2 * tk2 + 1;                     // tile for dbuf 1
        const int tp1 = (t1 + 1 < NTILES) ? t1 + 1 : t1; // prefetch for dbuf 0
        TILE(0, t1);
        TILE(1, tp1);
    }
    asm volatile("s_waitcnt vmcnt(0)" ::: "memory");

    // ---- fused LSTM epilogue, in-register ----
    // D layout: col = lane&15 (h), row = (lane>>4)*4 + reg
    const int rg = lane >> 4;
    const int h  = h0 + wn * 16 + lc;
    const float b_i = bh[0 * H_DIM + h];
    const float b_f = bh[1 * H_DIM + h];
    const float b_g = bh[2 * H_DIM + h];
    const float b_o = bh[3 * H_DIM + h];

    #pragma unroll
    for (int mf = 0; mf < 8; ++mf) {
        #pragma unroll
        for (int r = 0; r < 4; ++r) {
            const int row = m0 + wm * 128 + mf * 16 + rg * 4 + r;
            const float pi = acc[mf][0][r] + b_i;
            const float pf = acc[mf][1][r] + b_f;
            const float pg = acc[mf][2][r] + b_g;
            const float po = acc[mf][3][r] + b_o;
            const float iv = sigmoid_f(pi);
            const float fv = sigmoid_f(pf);
            const float gv = tanh_fast(pg);
            const float ov = sigmoid_f(po);
            const float cp = cprev[(size_t)row * H_DIM + h];
            const float cn = fv * cp + iv * gv;
            const float hn = ov * tanh_fast(cn);
            out[(size_t)row * H_DIM + h] = hn;
            out[(size_t)B_DIM * H_DIM + (size_t)row * H_DIM + h] = cn;
        }
    }
}

// ---------------------------------------------------------------------------
// Fallback (no workspace) — kept for safety.
// ---------------------------------------------------------------------------
static __device__ __forceinline__ int swz(int row, int k) {
    int byte = (row << 7) + (k << 1);
    byte ^= (row & 7) << 4;
    return byte >> 1;
}

__global__ __launch_bounds__(256, 2) void lstm_fallback_kernel(
    const float* __restrict__ x, const float* __restrict__ hprev,
    const float* __restrict__ cprev, const float* __restrict__ Wx,
    const float* __restrict__ Wh, const float* __restrict__ bh,
    float* __restrict__ out)
{
    __shared__ __align__(16) short As[128 * 64];
    __shared__ __align__(16) short Bs[128 * 64];

    int bid = blockIdx.x;
    bid = (bid & 7) * 256 + (bid >> 3);
    const int mt = bid >> 5;
    const int ht = bid & 31;
    const int m0 = mt * 128;
    const int h0 = ht * 32;

    const int t    = threadIdx.x;
    const int lane = t & 63;
    const int w    = t >> 6;
    const int wr   = w >> 1;
    const int wc   = w & 1;

    const int srow = t >> 3;
    const int sk   = (t & 7) * 8;

    f32x4 acc[4][4] = {};

    #pragma unroll 1
    for (int phase = 0; phase < 2; ++phase) {
        const float* __restrict__ Ap = phase ? hprev : x;
        const float* __restrict__ Bp = phase ? Wh : Wx;
        #pragma unroll 1
        for (int kk = 0; kk < 1024; kk += 64) {
            __syncthreads();
            #pragma unroll
            for (int p = 0; p < 4; ++p) {
                const int row = srow + p * 32;
                const float4* src = (const float4*)(Ap + (size_t)(m0 + row) * I_DIM + kk + sk);
                *(short8*)&As[swz(row, sk)] = pack8(src[0], src[1]);
            }
            #pragma unroll
            for (int p = 0; p < 4; ++p) {
                const int n    = srow + p * 32;
                const int gate = (n >> 4) & 3;
                const int hcol = h0 + ((n >> 6) << 4) + (n & 15);
                const float4* src = (const float4*)(Bp + (size_t)((gate << 10) + hcol) * 1024 + kk + sk);
                *(short8*)&Bs[swz(n, sk)] = pack8(src[0], src[1]);
            }
            __syncthreads();
            #pragma unroll
            for (int ks = 0; ks < 2; ++ks) {
                const int kb = ks * 32 + ((lane >> 4) << 3);
                short8 a[4], b[4];
                #pragma unroll
                for (int m = 0; m < 4; ++m)
                    a[m] = *(const short8*)&As[swz(wr * 64 + m * 16 + (lane & 15), kb)];
                #pragma unroll
                for (int j = 0; j < 4; ++j)
                    b[j] = *(const short8*)&Bs[swz(wc * 64 + j * 16 + (lane & 15), kb)];
                #pragma unroll
                for (int m = 0; m < 4; ++m)
                    #pragma unroll
                    for (int j = 0; j < 4; ++j)
                        acc[m][j] = __builtin_amdgcn_mfma_f32_16x16x32_bf16(a[m], b[j], acc[m][j], 0, 0, 0);
            }
        }
    }

    const int cl = lane & 15;
    const int rg = lane >> 4;
    const int h  = h0 + wc * 16 + cl;
    const float b_i = bh[0 * H_DIM + h];
    const float b_f = bh[1 * H_DIM + h];
    const float b_g = bh[2 * H_DIM + h];
    const float b_o = bh[3 * H_DIM + h];

    #pragma unroll
    for (int m = 0; m < 4; ++m) {
        #pragma unroll
        for (int r = 0; r < 4; ++r) {
            const int row = m0 + wr * 64 + m * 16 + rg * 4 + r;
            const float pi = acc[m][0][r] + b_i;
            const float pf = acc[m][1][r] + b_f;
            const float pg = acc[m][2][r] + b_g;
            const float po = acc[m][3][r] + b_o;
            const float iv = sigmoid_f(pi);
            const float fv = sigmoid_f(pf);
            const float gv = tanh_fast(pg);
            const float ov = sigmoid_f(po);
            const float cp = cprev[(size_t)row * H_DIM + h];
            const float cn = fv * cp + iv * gv;
            const float hn = ov * tanh_fast(cn);
            out[(size_t)row * H_DIM + h] = hn;
            out[(size_t)B_DIM * H_DIM + (size_t)row * H_DIM + h] = cn;
        }
    }
}

extern "C" void kernel_launch(void* const* d_in, const int* in_sizes, int n_in,
                              void* d_out, int out_size, void* d_ws, size_t ws_size,
                              hipStream_t stream) {
    const float* x     = (const float*)d_in[0];
    const float* hprev = (const float*)d_in[1];
    const float* cprev = (const float*)d_in[2];
    const float* Wx    = (const float*)d_in[3];
    const float* Wh    = (const float*)d_in[4];
    const float* bh    = (const float*)d_in[5];
    float* out = (float*)d_out;

    const size_t need = ((size_t)B_DIM * 2048 + (size_t)4096 * 2048) * sizeof(short);
    if (ws_size >= need && d_ws != nullptr) {
        (void)hipFuncSetAttribute((const void*)lstm_gemm8_kernel,
                                  hipFuncAttributeMaxDynamicSharedMemorySize, 131072);
        short* Aw = (short*)d_ws;
        short* Bw = Aw + (size_t)B_DIM * 2048;
        hipLaunchKernelGGL(convert_kernel, dim3(2048), dim3(256), 0, stream,
                           x, hprev, Wx, Wh, Aw, Bw);
        hipLaunchKernelGGL(lstm_gemm8_kernel, dim3(512), dim3(512), 131072, stream,
                           Aw, Bw, cprev, bh, out);
    } else {
        hipLaunchKernelGGL(lstm_fallback_kernel, dim3(2048), dim3(256), 0, stream,
                           x, hprev, cprev, Wx, Wh, bh, out);
    }
}

// Round 7
// 154.234 us; speedup vs baseline: 1.2463x; 1.2463x over previous
//
#include <hip/hip_runtime.h>
#include <hip/hip_bf16.h>
#include <stdint.h>

#define B_DIM 8192
#define I_DIM 1024
#define H_DIM 1024
#define KTOT  2048
#define NTILES 32          // KTOT / 64

typedef __attribute__((ext_vector_type(8))) short short8;
typedef __attribute__((ext_vector_type(4))) float f32x4;

static __device__ __forceinline__ short f2b(float f) {
    __bf16 h = (__bf16)f;
    return __builtin_bit_cast(short, h);
}

static __device__ __forceinline__ short8 pack8(float4 a, float4 b) {
    short8 s;
    s[0] = f2b(a.x); s[1] = f2b(a.y); s[2] = f2b(a.z); s[3] = f2b(a.w);
    s[4] = f2b(b.x); s[5] = f2b(b.y); s[6] = f2b(b.z); s[7] = f2b(b.w);
    return s;
}

static __device__ __forceinline__ float sigmoid_f(float x) {
    return 1.0f / (1.0f + __expf(-x));
}

static __device__ __forceinline__ float tanh_fast(float x) {
    x = fminf(fmaxf(x, -15.0f), 15.0f);
    float e = __expf(2.0f * x);
    return (e - 1.0f) / (e + 1.0f);
}

static __device__ __forceinline__ void load_lds16(const void* gptr, void* lptr) {
    __builtin_amdgcn_global_load_lds(
        (const __attribute__((address_space(1))) uint32_t*)gptr,
        (__attribute__((address_space(3))) uint32_t*)lptr, 16, 0, 0);
}

// ---------------------------------------------------------------------------
// Pass 1: fp32 -> bf16 conversion into FRAGMENT-ORDERED workspace.
//   A_fw: [mfrag 0..511][ktile 0..31][khalf 0..1][lane 0..63][8 bf16]
//         element: row = mfrag*16 + (lane&15), k = ktile*64 + khalf*32 + (lane>>4)*8
//         k<1024 from x, k>=1024 from hprev.
//   B_fw: [nfrag 0..255][ktile][khalf][lane][8]
//         nfrag = bn*16 + cf; gate = cf&3; col = bn*64 + (cf>>2)*16 + (lane&15)
//         k<1024 from Wx[gate][col], k>=1024 from Wh[gate][col].
// Every 64-lane group writes 1 KiB contiguous (dst = base + g*8), and the GEMM's
// global_load_lds sources become fully contiguous 1 KiB reads.
// ---------------------------------------------------------------------------
#define GA_GROUPS (512 * 32 * 2 * 64)   // 2,097,152  (A 16B-groups)
#define GB_GROUPS (256 * 32 * 2 * 64)   // 1,048,576  (B 16B-groups)

__global__ __launch_bounds__(256) void convert_kernel(
    const float* __restrict__ x, const float* __restrict__ h,
    const float* __restrict__ wx, const float* __restrict__ wh,
    short* __restrict__ Aw, short* __restrict__ Bw)
{
    const int64_t total = (int64_t)GA_GROUPS + GB_GROUPS;
    for (int64_t g = (int64_t)blockIdx.x * blockDim.x + threadIdx.x; g < total;
         g += (int64_t)gridDim.x * blockDim.x) {
        const float* src;
        short* dst;
        if (g < GA_GROUPS) {
            const int lane = (int)(g & 63);
            const int rest = (int)(g >> 6);
            const int kh   = rest & 1;
            const int tk   = (rest >> 1) & 31;
            const int mfrag = rest >> 6;
            const int row = (mfrag << 4) + (lane & 15);
            const int k   = (tk << 6) + (kh << 5) + ((lane >> 4) << 3);
            src = (k < 1024) ? (x + (size_t)row * 1024 + k)
                             : (h + (size_t)row * 1024 + (k - 1024));
            dst = Aw + (size_t)g * 8;
        } else {
            const int64_t gb = g - GA_GROUPS;
            const int lane = (int)(gb & 63);
            const int rest = (int)(gb >> 6);
            const int kh   = rest & 1;
            const int tk   = (rest >> 1) & 31;
            const int nfrag = rest >> 6;
            const int cf   = nfrag & 15;
            const int bn   = nfrag >> 4;
            const int gate = cf & 3;
            const int col  = (bn << 6) + ((cf >> 2) << 4) + (lane & 15);
            const int k    = (tk << 6) + (kh << 5) + ((lane >> 4) << 3);
            src = (k < 1024) ? (wx + ((size_t)(gate << 10) + col) * 1024 + k)
                             : (wh + ((size_t)(gate << 10) + col) * 1024 + (k - 1024));
            dst = Bw + (size_t)gb * 8;
        }
        float4 v0 = ((const float4*)src)[0];
        float4 v1 = ((const float4*)src)[1];
        *(short8*)dst = pack8(v0, v1);
    }
}

// ---------------------------------------------------------------------------
// Pass 2: 256x256-tile 8-phase GEMM, BK=64, counted vmcnt, reg double-buffered
// fragments, fragment-ordered workspace (contiguous 1 KiB gload_lds sources),
// fragment-tile LDS (zero bank conflicts). Fused in-register LSTM epilogue.
// 512 threads = 8 waves (2 M x 4 N); per-wave output 128 x 64 (4 gates x 16 h).
// LDS 128 KiB: A[2 dbuf][2 khalf][16 fragtile][1 KiB], B likewise.
// ---------------------------------------------------------------------------

#define AOFF(d, kp, f) ((d) * 16384 + (kp) * 8192 + (f) * 512)
#define BOFF(d, kp, f) (32768 + (d) * 16384 + (kp) * 8192 + (f) * 512)

// frag stride in shorts: 32 ktiles * 2 khalves * 512 shorts = 32768
#define STAGE_A(dn, kh, tkp) \
    load_lds16(aSrc0 + (tkp) * 1024 + (kh) * 512, &smem[AOFF(dn, kh, 2 * w)]); \
    load_lds16(aSrc1 + (tkp) * 1024 + (kh) * 512, &smem[AOFF(dn, kh, 2 * w + 1)]);

#define STAGE_B(dn, kh, tkp) \
    load_lds16(bSrc0 + (tkp) * 1024 + (kh) * 512, &smem[BOFF(dn, kh, 2 * w)]); \
    load_lds16(bSrc1 + (tkp) * 1024 + (kh) * 512, &smem[BOFF(dn, kh, 2 * w + 1)]);

#define VM4 asm volatile("s_waitcnt vmcnt(4)" ::: "memory");

// One phase: ds_reads into the phase-parity register buffer, stage-issue,
// barrier, MFMA cluster (compiler inserts precise lgkm waits), barrier.
#define PH(d, kp, mh, AV, BV, STAGE_STMT, EXTRAWAIT) do { \
    _Pragma("unroll") \
    for (int j = 0; j < 4; ++j) \
        BV[j] = *(const short8*)&smem[BOFF(d, kp, wn * 4 + j) + lane * 8]; \
    _Pragma("unroll") \
    for (int i = 0; i < 4; ++i) \
        AV[i] = *(const short8*)&smem[AOFF(d, kp, wm * 8 + (mh) * 4 + i) + lane * 8]; \
    STAGE_STMT \
    __builtin_amdgcn_s_barrier(); \
    __builtin_amdgcn_s_setprio(1); \
    _Pragma("unroll") \
    for (int i = 0; i < 4; ++i) \
        _Pragma("unroll") \
        for (int j = 0; j < 4; ++j) \
            acc[(mh) * 4 + i][j] = __builtin_amdgcn_mfma_f32_16x16x32_bf16( \
                AV[i], BV[j], acc[(mh) * 4 + i][j], 0, 0, 0); \
    __builtin_amdgcn_s_setprio(0); \
    EXTRAWAIT \
    __builtin_amdgcn_s_barrier(); \
} while (0)

#define TILE(d, tn) do { \
    PH(d, 0, 0, avA, bvA, STAGE_A(d ^ 1, 0, tn), ); \
    PH(d, 0, 1, avB, bvB, STAGE_B(d ^ 1, 0, tn), VM4); \
    PH(d, 1, 0, avA, bvA, STAGE_A(d ^ 1, 1, tn), ); \
    PH(d, 1, 1, avB, bvB, STAGE_B(d ^ 1, 1, tn), VM4); \
} while (0)

__global__ __launch_bounds__(512, 2) void lstm_gemm8_kernel(
    const short* __restrict__ Aw, const short* __restrict__ Bw,
    const float* __restrict__ cprev, const float* __restrict__ bh,
    float* __restrict__ out)
{
    extern __shared__ __align__(16) short smem[];

    // XCD-aware swizzle: 512 blocks, 8 XCDs, bijective
    int bid = blockIdx.x;
    bid = (bid & 7) * 64 + (bid >> 3);
    const int bm = bid >> 4;     // 0..31  M-tile (256 rows)
    const int bn = bid & 15;     // 0..15  h-tile (64 h)
    const int m0 = bm * 256;
    const int h0 = bn * 64;

    const int t    = threadIdx.x;
    const int lane = t & 63;
    const int w    = t >> 6;     // wave 0..7
    const int wm   = w >> 2;     // 0..1
    const int wn   = w & 3;      // 0..3
    const int lc   = lane & 15;

    // staging sources (fragment-ordered workspace, fully contiguous 1 KiB):
    // wave w stages fragtiles 2w, 2w+1. A frag index = bm*16 + f; B = bn*16 + f.
    const short* aSrc0 = Aw + (size_t)(bm * 16 + 2 * w + 0) * 32768 + lane * 8;
    const short* aSrc1 = Aw + (size_t)(bm * 16 + 2 * w + 1) * 32768 + lane * 8;
    const short* bSrc0 = Bw + (size_t)(bn * 16 + 2 * w + 0) * 32768 + lane * 8;
    const short* bSrc1 = Bw + (size_t)(bn * 16 + 2 * w + 1) * 32768 + lane * 8;

    f32x4 acc[8][4] = {};   // [m-frag][gate]
    short8 avA[4], avB[4], bvA[4], bvB[4];

    // prologue: stage tile 0 fully into dbuf 0, drain
    STAGE_A(0, 0, 0)
    STAGE_B(0, 0, 0)
    STAGE_A(0, 1, 0)
    STAGE_B(0, 1, 0)
    asm volatile("s_waitcnt vmcnt(0)" ::: "memory");
    __builtin_amdgcn_s_barrier();

    #pragma unroll 1
    for (int tk2 = 0; tk2 < 16; ++tk2) {
        const int t1  = 2 * tk2 + 1;                     // tile for dbuf 1
        const int tp1 = (t1 + 1 < NTILES) ? t1 + 1 : t1; // prefetch for dbuf 0
        TILE(0, t1);
        TILE(1, tp1);
    }
    asm volatile("s_waitcnt vmcnt(0)" ::: "memory");

    // ---- fused LSTM epilogue, in-register ----
    // D layout: col = lane&15 (h), row = (lane>>4)*4 + reg
    const int rg = lane >> 4;
    const int h  = h0 + wn * 16 + lc;
    const float b_i = bh[0 * H_DIM + h];
    const float b_f = bh[1 * H_DIM + h];
    const float b_g = bh[2 * H_DIM + h];
    const float b_o = bh[3 * H_DIM + h];

    #pragma unroll
    for (int mf = 0; mf < 8; ++mf) {
        #pragma unroll
        for (int r = 0; r < 4; ++r) {
            const int row = m0 + wm * 128 + mf * 16 + rg * 4 + r;
            const float pi = acc[mf][0][r] + b_i;
            const float pf = acc[mf][1][r] + b_f;
            const float pg = acc[mf][2][r] + b_g;
            const float po = acc[mf][3][r] + b_o;
            const float iv = sigmoid_f(pi);
            const float fv = sigmoid_f(pf);
            const float gv = tanh_fast(pg);
            const float ov = sigmoid_f(po);
            const float cp = cprev[(size_t)row * H_DIM + h];
            const float cn = fv * cp + iv * gv;
            const float hn = ov * tanh_fast(cn);
            out[(size_t)row * H_DIM + h] = hn;
            out[(size_t)B_DIM * H_DIM + (size_t)row * H_DIM + h] = cn;
        }
    }
}

// ---------------------------------------------------------------------------
// Fallback (no workspace) — kept for safety.
// ---------------------------------------------------------------------------
static __device__ __forceinline__ int swz(int row, int k) {
    int byte = (row << 7) + (k << 1);
    byte ^= (row & 7) << 4;
    return byte >> 1;
}

__global__ __launch_bounds__(256, 2) void lstm_fallback_kernel(
    const float* __restrict__ x, const float* __restrict__ hprev,
    const float* __restrict__ cprev, const float* __restrict__ Wx,
    const float* __restrict__ Wh, const float* __restrict__ bh,
    float* __restrict__ out)
{
    __shared__ __align__(16) short As[128 * 64];
    __shared__ __align__(16) short Bs[128 * 64];

    int bid = blockIdx.x;
    bid = (bid & 7) * 256 + (bid >> 3);
    const int mt = bid >> 5;
    const int ht = bid & 31;
    const int m0 = mt * 128;
    const int h0 = ht * 32;

    const int t    = threadIdx.x;
    const int lane = t & 63;
    const int w    = t >> 6;
    const int wr   = w >> 1;
    const int wc   = w & 1;

    const int srow = t >> 3;
    const int sk   = (t & 7) * 8;

    f32x4 acc[4][4] = {};

    #pragma unroll 1
    for (int phase = 0; phase < 2; ++phase) {
        const float* __restrict__ Ap = phase ? hprev : x;
        const float* __restrict__ Bp = phase ? Wh : Wx;
        #pragma unroll 1
        for (int kk = 0; kk < 1024; kk += 64) {
            __syncthreads();
            #pragma unroll
            for (int p = 0; p < 4; ++p) {
                const int row = srow + p * 32;
                const float4* src = (const float4*)(Ap + (size_t)(m0 + row) * I_DIM + kk + sk);
                *(short8*)&As[swz(row, sk)] = pack8(src[0], src[1]);
            }
            #pragma unroll
            for (int p = 0; p < 4; ++p) {
                const int n    = srow + p * 32;
                const int gate = (n >> 4) & 3;
                const int hcol = h0 + ((n >> 6) << 4) + (n & 15);
                const float4* src = (const float4*)(Bp + (size_t)((gate << 10) + hcol) * 1024 + kk + sk);
                *(short8*)&Bs[swz(n, sk)] = pack8(src[0], src[1]);
            }
            __syncthreads();
            #pragma unroll
            for (int ks = 0; ks < 2; ++ks) {
                const int kb = ks * 32 + ((lane >> 4) << 3);
                short8 a[4], b[4];
                #pragma unroll
                for (int m = 0; m < 4; ++m)
                    a[m] = *(const short8*)&As[swz(wr * 64 + m * 16 + (lane & 15), kb)];
                #pragma unroll
                for (int j = 0; j < 4; ++j)
                    b[j] = *(const short8*)&Bs[swz(wc * 64 + j * 16 + (lane & 15), kb)];
                #pragma unroll
                for (int m = 0; m < 4; ++m)
                    #pragma unroll
                    for (int j = 0; j < 4; ++j)
                        acc[m][j] = __builtin_amdgcn_mfma_f32_16x16x32_bf16(a[m], b[j], acc[m][j], 0, 0, 0);
            }
        }
    }

    const int cl = lane & 15;
    const int rg = lane >> 4;
    const int h  = h0 + wc * 16 + cl;
    const float b_i = bh[0 * H_DIM + h];
    const float b_f = bh[1 * H_DIM + h];
    const float b_g = bh[2 * H_DIM + h];
    const float b_o = bh[3 * H_DIM + h];

    #pragma unroll
    for (int m = 0; m < 4; ++m) {
        #pragma unroll
        for (int r = 0; r < 4; ++r) {
            const int row = m0 + wr * 64 + m * 16 + rg * 4 + r;
            const float pi = acc[m][0][r] + b_i;
            const float pf = acc[m][1][r] + b_f;
            const float pg = acc[m][2][r] + b_g;
            const float po = acc[m][3][r] + b_o;
            const float iv = sigmoid_f(pi);
            const float fv = sigmoid_f(pf);
            const float gv = tanh_fast(pg);
            const float ov = sigmoid_f(po);
            const float cp = cprev[(size_t)row * H_DIM + h];
            const float cn = fv * cp + iv * gv;
            const float hn = ov * tanh_fast(cn);
            out[(size_t)row * H_DIM + h] = hn;
            out[(size_t)B_DIM * H_DIM + (size_t)row * H_DIM + h] = cn;
        }
    }
}

extern "C" void kernel_launch(void* const* d_in, const int* in_sizes, int n_in,
                              void* d_out, int out_size, void* d_ws, size_t ws_size,
                              hipStream_t stream) {
    const float* x     = (const float*)d_in[0];
    const float* hprev = (const float*)d_in[1];
    const float* cprev = (const float*)d_in[2];
    const float* Wx    = (const float*)d_in[3];
    const float* Wh    = (const float*)d_in[4];
    const float* bh    = (const float*)d_in[5];
    float* out = (float*)d_out;

    const size_t need = ((size_t)B_DIM * 2048 + (size_t)4096 * 2048) * sizeof(short);
    if (ws_size >= need && d_ws != nullptr) {
        (void)hipFuncSetAttribute((const void*)lstm_gemm8_kernel,
                                  hipFuncAttributeMaxDynamicSharedMemorySize, 131072);
        short* Aw = (short*)d_ws;                       // A_fw: 512 frags * 32768 shorts
        short* Bw = Aw + (size_t)512 * 32768;           // B_fw: 256 frags * 32768 shorts
        hipLaunchKernelGGL(convert_kernel, dim3(4096), dim3(256), 0, stream,
                           x, hprev, Wx, Wh, Aw, Bw);
        hipLaunchKernelGGL(lstm_gemm8_kernel, dim3(512), dim3(512), 131072, stream,
                           Aw, Bw, cprev, bh, out);
    } else {
        hipLaunchKernelGGL(lstm_fallback_kernel, dim3(2048), dim3(256), 0, stream,
                           x, hprev, cprev, Wx, Wh, bh, out);
    }
}

// Round 8
// 149.063 us; speedup vs baseline: 1.2895x; 1.0347x over previous
//
#include <hip/hip_runtime.h>
#include <hip/hip_bf16.h>
#include <stdint.h>

#define B_DIM 8192
#define I_DIM 1024
#define H_DIM 1024

typedef __attribute__((ext_vector_type(8))) short short8;
typedef __attribute__((ext_vector_type(4))) float f32x4;

static __device__ __forceinline__ short f2b(float f) {
    __bf16 h = (__bf16)f;
    return __builtin_bit_cast(short, h);
}

static __device__ __forceinline__ short8 pack8(float4 a, float4 b) {
    short8 s;
    s[0] = f2b(a.x); s[1] = f2b(a.y); s[2] = f2b(a.z); s[3] = f2b(a.w);
    s[4] = f2b(b.x); s[5] = f2b(b.y); s[6] = f2b(b.z); s[7] = f2b(b.w);
    return s;
}

static __device__ __forceinline__ float sigmoid_f(float x) {
    return 1.0f / (1.0f + __expf(-x));
}

static __device__ __forceinline__ float tanh_fast(float x) {
    x = fminf(fmaxf(x, -15.0f), 15.0f);
    float e = __expf(2.0f * x);
    return (e - 1.0f) / (e + 1.0f);
}

static __device__ __forceinline__ void load_lds16(const void* gptr, void* lptr) {
    __builtin_amdgcn_global_load_lds(
        (const __attribute__((address_space(1))) uint32_t*)gptr,
        (__attribute__((address_space(3))) uint32_t*)lptr, 16, 0, 0);
}

// ---------------------------------------------------------------------------
// Pass 1: fp32 -> bf16 conversion into FRAGMENT-ORDERED workspace (unchanged
// from round 7; [ktile][khalf] axes here are read by the GEMM as one [k32]).
//   A_fw: [mfrag 0..511][k32 0..63][lane 0..63][8 bf16]
//         row = mfrag*16 + (lane&15), k = k32*32 + (lane>>4)*8
//   B_fw: [nfrag 0..255][k32][lane][8]
//         nfrag = bn*16 + cf; gate = cf&3; col = bn*64 + (cf>>2)*16 + (lane&15)
// ---------------------------------------------------------------------------
#define GA_GROUPS (512 * 32 * 2 * 64)   // 2,097,152  (A 16B-groups)
#define GB_GROUPS (256 * 32 * 2 * 64)   // 1,048,576  (B 16B-groups)

__global__ __launch_bounds__(256) void convert_kernel(
    const float* __restrict__ x, const float* __restrict__ h,
    const float* __restrict__ wx, const float* __restrict__ wh,
    short* __restrict__ Aw, short* __restrict__ Bw)
{
    const int64_t total = (int64_t)GA_GROUPS + GB_GROUPS;
    for (int64_t g = (int64_t)blockIdx.x * blockDim.x + threadIdx.x; g < total;
         g += (int64_t)gridDim.x * blockDim.x) {
        const float* src;
        short* dst;
        if (g < GA_GROUPS) {
            const int lane = (int)(g & 63);
            const int rest = (int)(g >> 6);
            const int kh   = rest & 1;
            const int tk   = (rest >> 1) & 31;
            const int mfrag = rest >> 6;
            const int row = (mfrag << 4) + (lane & 15);
            const int k   = (tk << 6) + (kh << 5) + ((lane >> 4) << 3);
            src = (k < 1024) ? (x + (size_t)row * 1024 + k)
                             : (h + (size_t)row * 1024 + (k - 1024));
            dst = Aw + (size_t)g * 8;
        } else {
            const int64_t gb = g - GA_GROUPS;
            const int lane = (int)(gb & 63);
            const int rest = (int)(gb >> 6);
            const int kh   = rest & 1;
            const int tk   = (rest >> 1) & 31;
            const int nfrag = rest >> 6;
            const int cf   = nfrag & 15;
            const int bn   = nfrag >> 4;
            const int gate = cf & 3;
            const int col  = (bn << 6) + ((cf >> 2) << 4) + (lane & 15);
            const int k    = (tk << 6) + (kh << 5) + ((lane >> 4) << 3);
            src = (k < 1024) ? (wx + ((size_t)(gate << 10) + col) * 1024 + k)
                             : (wh + ((size_t)(gate << 10) + col) * 1024 + (k - 1024));
            dst = Bw + (size_t)gb * 8;
        }
        float4 v0 = ((const float4*)src)[0];
        float4 v1 = ((const float4*)src)[1];
        *(short8*)dst = pack8(v0, v1);
    }
}

// ---------------------------------------------------------------------------
// Pass 2: 128x256-tile GEMM, BK=32, 48 KiB LDS -> 2 BLOCKS/CU (cross-block
// TLP overlaps one block's LDS-read bursts with the other's MFMA bursts).
// 8 waves (2M x 4N), per-wave 64 rows x 64 cols (4 gates x 16 h), acc 64 VGPR.
// One barrier + one vmcnt(0) per K-tile. Fragment-ordered workspace
// (contiguous 1 KiB gload_lds), fragment-tile LDS (zero bank conflicts).
// Fused in-register LSTM epilogue.
// LDS: [2 dbuf][ A 8 frags | B 16 frags ][512 shorts] = 48 KiB.
// ---------------------------------------------------------------------------
__global__ __launch_bounds__(512, 4) void lstm_gemm_tlp_kernel(
    const short* __restrict__ Aw, const short* __restrict__ Bw,
    const float* __restrict__ cprev, const float* __restrict__ bh,
    float* __restrict__ out)
{
    __shared__ __align__(16) short smem[24576];   // 48 KiB

    // L2-aware placement: hw round-robins blockIdx -> XCD, so xcd = bid&7.
    // Each XCD works bn in {2*xcd, 2*xcd+1}: its 2 MB B-slice stays L2-resident.
    const int bid = blockIdx.x;
    const int xcd = bid & 7;
    const int c   = bid >> 3;            // 0..127 within XCD
    const int bm  = c >> 1;              // 0..63   (128-row M tiles)
    const int bn  = 2 * xcd + (c & 1);   // 0..15   (64-h N tiles)
    const int m0  = bm * 128;
    const int h0  = bn * 64;

    const int t    = threadIdx.x;
    const int lane = t & 63;
    const int w    = t >> 6;     // wave 0..7
    const int wm   = w >> 2;     // 0..1  M half
    const int wn   = w & 3;      // 0..3  N quarter (h-group)
    const int lc   = lane & 15;

    // staging sources (contiguous 1 KiB per gload): wave w stages
    // A-frag f=w and B-frags 2w, 2w+1. Frag stride = 64 k32-tiles * 512 shorts.
    const short* aSrc  = Aw + (size_t)(bm * 8  + w)         * 32768 + lane * 8;
    const short* bSrc0 = Bw + (size_t)(bn * 16 + 2 * w)     * 32768 + lane * 8;
    const short* bSrc1 = Bw + (size_t)(bn * 16 + 2 * w + 1) * 32768 + lane * 8;

    f32x4 acc[4][4] = {};   // [m-frag][gate]

    // prologue: stage k32-tile 0 into dbuf 0
    load_lds16(aSrc,  &smem[w * 512]);
    load_lds16(bSrc0, &smem[4096 + (2 * w) * 512]);
    load_lds16(bSrc1, &smem[4096 + (2 * w + 1) * 512]);
    asm volatile("s_waitcnt vmcnt(0)" ::: "memory");
    __builtin_amdgcn_s_barrier();

    #pragma unroll 1
    for (int tk = 0; tk < 64; ++tk) {
        const int d  = (tk & 1) * 12288;       // current buffer
        const int dn = 12288 - d;              // next buffer
        const int tp = (tk + 1 < 64) ? tk + 1 : tk;

        short8 bv[4], av[4];
        #pragma unroll
        for (int j = 0; j < 4; ++j)
            bv[j] = *(const short8*)&smem[d + 4096 + (wn * 4 + j) * 512 + lane * 8];
        #pragma unroll
        for (int i = 0; i < 4; ++i)
            av[i] = *(const short8*)&smem[d + (wm * 4 + i) * 512 + lane * 8];

        // issue next-tile staging early (hides under MFMAs)
        load_lds16(aSrc  + tp * 512, &smem[dn + w * 512]);
        load_lds16(bSrc0 + tp * 512, &smem[dn + 4096 + (2 * w) * 512]);
        load_lds16(bSrc1 + tp * 512, &smem[dn + 4096 + (2 * w + 1) * 512]);

        __builtin_amdgcn_s_setprio(1);
        #pragma unroll
        for (int i = 0; i < 4; ++i)
            #pragma unroll
            for (int j = 0; j < 4; ++j)
                acc[i][j] = __builtin_amdgcn_mfma_f32_16x16x32_bf16(
                    av[i], bv[j], acc[i][j], 0, 0, 0);
        __builtin_amdgcn_s_setprio(0);

        asm volatile("s_waitcnt vmcnt(0)" ::: "memory");
        __builtin_amdgcn_s_barrier();
    }

    // ---- fused LSTM epilogue, in-register ----
    // D layout: col = lane&15 (h), row = (lane>>4)*4 + reg
    const int rg = lane >> 4;
    const int h  = h0 + wn * 16 + lc;
    const float b_i = bh[0 * H_DIM + h];
    const float b_f = bh[1 * H_DIM + h];
    const float b_g = bh[2 * H_DIM + h];
    const float b_o = bh[3 * H_DIM + h];

    #pragma unroll
    for (int mf = 0; mf < 4; ++mf) {
        #pragma unroll
        for (int r = 0; r < 4; ++r) {
            const int row = m0 + wm * 64 + mf * 16 + rg * 4 + r;
            const float pi = acc[mf][0][r] + b_i;
            const float pf = acc[mf][1][r] + b_f;
            const float pg = acc[mf][2][r] + b_g;
            const float po = acc[mf][3][r] + b_o;
            const float iv = sigmoid_f(pi);
            const float fv = sigmoid_f(pf);
            const float gv = tanh_fast(pg);
            const float ov = sigmoid_f(po);
            const float cp = cprev[(size_t)row * H_DIM + h];
            const float cn = fv * cp + iv * gv;
            const float hn = ov * tanh_fast(cn);
            out[(size_t)row * H_DIM + h] = hn;
            out[(size_t)B_DIM * H_DIM + (size_t)row * H_DIM + h] = cn;
        }
    }
}

// ---------------------------------------------------------------------------
// Fallback (no workspace) — kept for safety.
// ---------------------------------------------------------------------------
static __device__ __forceinline__ int swz(int row, int k) {
    int byte = (row << 7) + (k << 1);
    byte ^= (row & 7) << 4;
    return byte >> 1;
}

__global__ __launch_bounds__(256, 2) void lstm_fallback_kernel(
    const float* __restrict__ x, const float* __restrict__ hprev,
    const float* __restrict__ cprev, const float* __restrict__ Wx,
    const float* __restrict__ Wh, const float* __restrict__ bh,
    float* __restrict__ out)
{
    __shared__ __align__(16) short As[128 * 64];
    __shared__ __align__(16) short Bs[128 * 64];

    int bid = blockIdx.x;
    bid = (bid & 7) * 256 + (bid >> 3);
    const int mt = bid >> 5;
    const int ht = bid & 31;
    const int m0 = mt * 128;
    const int h0 = ht * 32;

    const int t    = threadIdx.x;
    const int lane = t & 63;
    const int w    = t >> 6;
    const int wr   = w >> 1;
    const int wc   = w & 1;

    const int srow = t >> 3;
    const int sk   = (t & 7) * 8;

    f32x4 acc[4][4] = {};

    #pragma unroll 1
    for (int phase = 0; phase < 2; ++phase) {
        const float* __restrict__ Ap = phase ? hprev : x;
        const float* __restrict__ Bp = phase ? Wh : Wx;
        #pragma unroll 1
        for (int kk = 0; kk < 1024; kk += 64) {
            __syncthreads();
            #pragma unroll
            for (int p = 0; p < 4; ++p) {
                const int row = srow + p * 32;
                const float4* src = (const float4*)(Ap + (size_t)(m0 + row) * I_DIM + kk + sk);
                *(short8*)&As[swz(row, sk)] = pack8(src[0], src[1]);
            }
            #pragma unroll
            for (int p = 0; p < 4; ++p) {
                const int n    = srow + p * 32;
                const int gate = (n >> 4) & 3;
                const int hcol = h0 + ((n >> 6) << 4) + (n & 15);
                const float4* src = (const float4*)(Bp + (size_t)((gate << 10) + hcol) * 1024 + kk + sk);
                *(short8*)&Bs[swz(n, sk)] = pack8(src[0], src[1]);
            }
            __syncthreads();
            #pragma unroll
            for (int ks = 0; ks < 2; ++ks) {
                const int kb = ks * 32 + ((lane >> 4) << 3);
                short8 a[4], b[4];
                #pragma unroll
                for (int m = 0; m < 4; ++m)
                    a[m] = *(const short8*)&As[swz(wr * 64 + m * 16 + (lane & 15), kb)];
                #pragma unroll
                for (int j = 0; j < 4; ++j)
                    b[j] = *(const short8*)&Bs[swz(wc * 64 + j * 16 + (lane & 15), kb)];
                #pragma unroll
                for (int m = 0; m < 4; ++m)
                    #pragma unroll
                    for (int j = 0; j < 4; ++j)
                        acc[m][j] = __builtin_amdgcn_mfma_f32_16x16x32_bf16(a[m], b[j], acc[m][j], 0, 0, 0);
            }
        }
    }

    const int cl = lane & 15;
    const int rg = lane >> 4;
    const int h  = h0 + wc * 16 + cl;
    const float b_i = bh[0 * H_DIM + h];
    const float b_f = bh[1 * H_DIM + h];
    const float b_g = bh[2 * H_DIM + h];
    const float b_o = bh[3 * H_DIM + h];

    #pragma unroll
    for (int m = 0; m < 4; ++m) {
        #pragma unroll
        for (int r = 0; r < 4; ++r) {
            const int row = m0 + wr * 64 + m * 16 + rg * 4 + r;
            const float pi = acc[m][0][r] + b_i;
            const float pf = acc[m][1][r] + b_f;
            const float pg = acc[m][2][r] + b_g;
            const float po = acc[m][3][r] + b_o;
            const float iv = sigmoid_f(pi);
            const float fv = sigmoid_f(pf);
            const float gv = tanh_fast(pg);
            const float ov = sigmoid_f(po);
            const float cp = cprev[(size_t)row * H_DIM + h];
            const float cn = fv * cp + iv * gv;
            const float hn = ov * tanh_fast(cn);
            out[(size_t)row * H_DIM + h] = hn;
            out[(size_t)B_DIM * H_DIM + (size_t)row * H_DIM + h] = cn;
        }
    }
}

extern "C" void kernel_launch(void* const* d_in, const int* in_sizes, int n_in,
                              void* d_out, int out_size, void* d_ws, size_t ws_size,
                              hipStream_t stream) {
    const float* x     = (const float*)d_in[0];
    const float* hprev = (const float*)d_in[1];
    const float* cprev = (const float*)d_in[2];
    const float* Wx    = (const float*)d_in[3];
    const float* Wh    = (const float*)d_in[4];
    const float* bh    = (const float*)d_in[5];
    float* out = (float*)d_out;

    const size_t need = ((size_t)B_DIM * 2048 + (size_t)4096 * 2048) * sizeof(short);
    if (ws_size >= need && d_ws != nullptr) {
        short* Aw = (short*)d_ws;                 // A_fw: 512 frags * 32768 shorts
        short* Bw = Aw + (size_t)512 * 32768;     // B_fw: 256 frags * 32768 shorts
        hipLaunchKernelGGL(convert_kernel, dim3(4096), dim3(256), 0, stream,
                           x, hprev, Wx, Wh, Aw, Bw);
        hipLaunchKernelGGL(lstm_gemm_tlp_kernel, dim3(1024), dim3(512), 0, stream,
                           Aw, Bw, cprev, bh, out);
    } else {
        hipLaunchKernelGGL(lstm_fallback_kernel, dim3(2048), dim3(256), 0, stream,
                           x, hprev, cprev, Wx, Wh, bh, out);
    }
}